// Round 1
// baseline (257.518 us; speedup 1.0000x reference)
//
#include <hip/hip_runtime.h>

#define B_ 8
#define N_ 1568
#define C_ 384
#define H_ 6
#define D_ 64
#define BH_ 48
#define SZ_ (B_*H_*N_*D_)
#define EPS_ 1e-6f
#define EPSN_ (EPS_/(float)N_)
#define CSC_ 0.18033688011112042f  /* D^-0.5 * log2(e) */

typedef short s16x8 __attribute__((ext_vector_type(8)));
typedef float f32x4 __attribute__((ext_vector_type(4)));

static __device__ __forceinline__ ushort f2bf(float f){
  union { float f; unsigned u; } v; v.f = f;
  unsigned r = v.u + 0x7fffu + ((v.u >> 16) & 1u);
  return (ushort)(r >> 16);
}
static __device__ __forceinline__ float bf2f(ushort u){
  union { unsigned u; float f; } v; v.u = ((unsigned)u) << 16; return v.f;
}
static __device__ __forceinline__ s16x8 pack8(float4 a, float4 b){
  s16x8 r;
  r[0]=(short)f2bf(a.x); r[1]=(short)f2bf(a.y); r[2]=(short)f2bf(a.z); r[3]=(short)f2bf(a.w);
  r[4]=(short)f2bf(b.x); r[5]=(short)f2bf(b.y); r[6]=(short)f2bf(b.z); r[7]=(short)f2bf(b.w);
  return r;
}
#define MFMA16(a,b,c) __builtin_amdgcn_mfma_f32_16x16x32_bf16((a),(b),(c),0,0,0)

#if __has_builtin(__builtin_amdgcn_exp2f)
#define EXP2F(x) __builtin_amdgcn_exp2f(x)
#else
#define EXP2F(x) exp2f(x)
#endif

#if __has_builtin(__builtin_amdgcn_update_dpp)
#define ROT16(x,c) __int_as_float(__builtin_amdgcn_update_dpp(0, __float_as_int(x), (c), 0xf, 0xf, true))
static __device__ __forceinline__ float rmax16(float x){
  x = fmaxf(x, ROT16(x,0x121)); x = fmaxf(x, ROT16(x,0x122));
  x = fmaxf(x, ROT16(x,0x124)); x = fmaxf(x, ROT16(x,0x128)); return x;
}
static __device__ __forceinline__ float rsum16(float x){
  x += ROT16(x,0x121); x += ROT16(x,0x122); x += ROT16(x,0x124); x += ROT16(x,0x128); return x;
}
#else
static __device__ __forceinline__ float rmax16(float x){
  x = fmaxf(x, __shfl_xor(x,1)); x = fmaxf(x, __shfl_xor(x,2));
  x = fmaxf(x, __shfl_xor(x,4)); x = fmaxf(x, __shfl_xor(x,8)); return x;
}
static __device__ __forceinline__ float rsum16(float x){
  x += __shfl_xor(x,1); x += __shfl_xor(x,2); x += __shfl_xor(x,4); x += __shfl_xor(x,8); return x;
}
#endif

// ---------------- QKV GEMM: qkv = x @ w_qkv^T, scatter to Q,K,V bf16 [B,H,N,D] ----------------
__global__ __launch_bounds__(256) void qkv_gemm(const float* __restrict__ X, const float* __restrict__ W,
                                                ushort* __restrict__ Qg, ushort* __restrict__ Kg,
                                                ushort* __restrict__ Vg){
  __shared__ __align__(16) ushort Al[128*40];
  __shared__ __align__(16) ushort Bl[64*40];
  const int tid = threadIdx.x, lane = tid&63, w = tid>>6;
  const int g = lane>>4, lr = lane&15;
  const int wr = w>>1, wc = w&1;
  const int m0 = blockIdx.x*128, j0 = blockIdx.y*64;
  const int ar = tid>>1, ah = tid&1;
  const int br = tid>>2, bq = tid&3;
  f32x4 acc[4][2];
  #pragma unroll
  for (int i=0;i<4;i++){ acc[i][0]=(f32x4){0.f,0.f,0.f,0.f}; acc[i][1]=(f32x4){0.f,0.f,0.f,0.f}; }

  for (int ks=0; ks<384; ks+=32){
    const float* as = X + (size_t)(m0+ar)*384 + ks + ah*16;
    float4 a0 = ((const float4*)as)[0], a1 = ((const float4*)as)[1];
    float4 a2 = ((const float4*)as)[2], a3 = ((const float4*)as)[3];
    const float* bs = W + (size_t)(j0+br)*384 + ks + bq*8;
    float4 b0 = ((const float4*)bs)[0], b1 = ((const float4*)bs)[1];
    *(s16x8*)&Al[ar*40 + ah*16]     = pack8(a0,a1);
    *(s16x8*)&Al[ar*40 + ah*16 + 8] = pack8(a2,a3);
    *(s16x8*)&Bl[br*40 + bq*8]      = pack8(b0,b1);
    __syncthreads();
    s16x8 af[4], bf[2];
    #pragma unroll
    for (int fm=0; fm<4; fm++) af[fm] = *(const s16x8*)&Al[(wr*64+fm*16+lr)*40 + g*8];
    #pragma unroll
    for (int fn=0; fn<2; fn++) bf[fn] = *(const s16x8*)&Bl[(wc*32+fn*16+lr)*40 + g*8];
    #pragma unroll
    for (int fm=0; fm<4; fm++)
      #pragma unroll
      for (int fn=0; fn<2; fn++)
        acc[fm][fn] = MFMA16(af[fm], bf[fn], acc[fm][fn]);
    __syncthreads();
  }
  const int t = j0/384, h = (j0%384)/64;
  #pragma unroll
  for (int fm=0; fm<4; fm++){
    #pragma unroll
    for (int jj=0; jj<4; jj++){
      int m = m0 + wr*64 + fm*16 + g*4 + jj;
      int bi = m / N_; int n = m - bi*N_;
      #pragma unroll
      for (int fn=0; fn<2; fn++){
        int d = wc*32 + fn*16 + lr;
        float v = acc[fm][fn][jj];
        int idx = ((bi*H_ + h)*N_ + n)*64 + d;
        if (t==0)      Qg[idx] = f2bf(v * CSC_);   // fold scale*log2e into Q
        else if (t==1) Kg[idx] = f2bf(v);
        else           Vg[idx] = f2bf(v);
      }
    }
  }
}

// ---------------- fused flash attention with policy-softmax ----------------
__global__ __launch_bounds__(256) void attn_fwd(const ushort* __restrict__ Qg, const ushort* __restrict__ Kg,
                                                const ushort* __restrict__ Vg, const float* __restrict__ pol_g,
                                                ushort* __restrict__ AO){
  __shared__ __align__(16) char smem[15104];
  ushort* Klds = (ushort*)smem;                // [32][72] padded
  ushort* Vtld = (ushort*)(smem + 4608);       // [64][40] transposed V tile
  ushort* Plds = (ushort*)(smem + 9728);       // per-wave [16][40]
  float*  pols = (float*)(smem + 14848);       // [32]
  float*  red  = (float*)smem;                 // epilogue reuse (8 KB)
  __shared__ float sumv_s[64];

  const int tid = threadIdx.x, lane = tid&63, w = tid>>6;
  const int g = lane>>4, lr = lane&15;
  const int bh = blockIdx.x; const int b = bh / H_, h = bh - b*H_;
  const int q0 = blockIdx.y*64;
  const int qrow0 = q0 + w*16;
  const int qn = qrow0 + lr;
  const int qnc = qn < N_ ? qn : N_-1;
  const ushort* Qrow = Qg + ((size_t)bh*N_ + qnc)*64;
  const s16x8 qf0 = *(const s16x8*)(Qrow + g*8);
  const s16x8 qf1 = *(const s16x8*)(Qrow + 32 + g*8);
  ushort* Pw = Plds + w*(16*40);
  const float* polp = pol_g + b*N_;

  const int kk = tid>>3, kc = tid&7;     // K staging: key row, 8-elem chunk
  const int vk = tid&31, vc = tid>>5;    // V staging: key row, d chunk

  f32x4 o[4];
  #pragma unroll
  for (int i=0;i<4;i++) o[i] = (f32x4){0.f,0.f,0.f,0.f};
  float M[4] = {-INFINITY,-INFINITY,-INFINITY,-INFINITY};
  float L[4] = {0.f,0.f,0.f,0.f};
  float vpart[8] = {0.f,0.f,0.f,0.f,0.f,0.f,0.f,0.f};

  for (int t0=0; t0<N_; t0+=32){
    // stage K tile [32][64] -> padded LDS
    s16x8 kvv = *(const s16x8*)(Kg + ((size_t)bh*N_ + t0 + kk)*64 + kc*8);
    *(s16x8*)(Klds + kk*72 + kc*8) = kvv;
    // stage V tile transposed -> Vtld[d][key]; accumulate unweighted sum(V) for EPS term
    s16x8 vvv = *(const s16x8*)(Vg + ((size_t)bh*N_ + t0 + vk)*64 + vc*8);
    #pragma unroll
    for (int i=0;i<8;i++){
      Vtld[(vc*8+i)*40 + vk] = (ushort)vvv[i];
      vpart[i] += bf2f((ushort)vvv[i]);
    }
    if (tid < 32) pols[tid] = polp[t0 + tid];
    __syncthreads();

    // S = Q K^T (Q pre-scaled, so S is in log2 units)
    f32x4 s0 = (f32x4){0.f,0.f,0.f,0.f}, s1 = (f32x4){0.f,0.f,0.f,0.f};
    {
      const ushort* kb0 = Klds + (size_t)lr*72;
      const ushort* kb1 = Klds + (size_t)(16+lr)*72;
      s0 = MFMA16(qf0, *(const s16x8*)(kb0 + g*8), s0);
      s0 = MFMA16(qf1, *(const s16x8*)(kb0 + 32 + g*8), s0);
      s1 = MFMA16(qf0, *(const s16x8*)(kb1 + g*8), s1);
      s1 = MFMA16(qf1, *(const s16x8*)(kb1 + 32 + g*8), s1);
    }
    float p0 = pols[lr], p1 = pols[16+lr];
    int key0 = t0 + lr, key1 = t0 + 16 + lr;
    #pragma unroll
    for (int jj=0; jj<4; jj++){
      float a0 = s0[jj], a1 = s1[jj];
      float mj = rmax16(fmaxf(a0, a1));          // max over ALL logits (pre-mask), as reference
      float Mn = fmaxf(M[jj], mj);
      float corr = EXP2F(M[jj] - Mn);
      int rowg = qrow0 + g*4 + jj;
      float e0 = EXP2F(a0 - Mn);
      float e1 = EXP2F(a1 - Mn);
      e0 = (p0 != 0.f || key0 == rowg) ? e0 : 0.f;  // policy mask, diagonal always kept
      e1 = (p1 != 0.f || key1 == rowg) ? e1 : 0.f;
      float se = rsum16(e0 + e1);
      L[jj] = L[jj]*corr + se;
      M[jj] = Mn;
      o[0][jj]*=corr; o[1][jj]*=corr; o[2][jj]*=corr; o[3][jj]*=corr;
      Pw[(g*4+jj)*40 + lr]      = f2bf(e0);
      Pw[(g*4+jj)*40 + 16 + lr] = f2bf(e1);
    }
    asm volatile("s_waitcnt lgkmcnt(0)" ::: "memory");
    __builtin_amdgcn_sched_barrier(0);
    const s16x8 pa = *(const s16x8*)(Pw + (size_t)lr*40 + g*8);
    #pragma unroll
    for (int fd=0; fd<4; fd++){
      const s16x8 vb = *(const s16x8*)(Vtld + (size_t)(fd*16+lr)*40 + g*8);
      o[fd] = MFMA16(pa, vb, o[fd]);
    }
    __syncthreads();
  }

  // block-wide reduce of unweighted sum(V) -> sumv_s[d]
  #pragma unroll
  for (int i=0;i<8;i++) red[tid*8+i] = vpart[i];
  __syncthreads();
  if (tid < 64){
    float s = 0.f; int c = tid>>3, i = tid&7;
    for (int key=0; key<32; key++) s += red[(c*32+key)*8 + i];
    sumv_s[tid] = s;
  }
  __syncthreads();

  float sv[4];
  #pragma unroll
  for (int fd=0; fd<4; fd++) sv[fd] = sumv_s[fd*16 + lr];
  #pragma unroll
  for (int jj=0; jj<4; jj++){
    int rowg = qrow0 + g*4 + jj;
    if (rowg < N_){
      float inv = 1.f / (L[jj] + EPS_);
      #pragma unroll
      for (int fd=0; fd<4; fd++){
        float val = (o[fd][jj] + EPSN_*sv[fd]) * inv;
        AO[((size_t)b*N_ + rowg)*C_ + h*64 + fd*16 + lr] = f2bf(val);
      }
    }
  }
}

// ---------------- proj GEMM: out = AO @ w_proj^T + b, f32 out ----------------
__global__ __launch_bounds__(256) void proj_gemm(const ushort* __restrict__ A, const float* __restrict__ W,
                                                 const float* __restrict__ bias, float* __restrict__ out){
  __shared__ __align__(16) ushort Al[128*40];
  __shared__ __align__(16) ushort Bl[64*40];
  const int tid = threadIdx.x, lane = tid&63, w = tid>>6;
  const int g = lane>>4, lr = lane&15;
  const int wr = w>>1, wc = w&1;
  const int m0 = blockIdx.x*128, j0 = blockIdx.y*64;
  const int ar = tid>>1, ah = tid&1;
  const int br = tid>>2, bq = tid&3;
  f32x4 acc[4][2];
  #pragma unroll
  for (int i=0;i<4;i++){ acc[i][0]=(f32x4){0.f,0.f,0.f,0.f}; acc[i][1]=(f32x4){0.f,0.f,0.f,0.f}; }

  for (int ks=0; ks<384; ks+=32){
    const ushort* as = A + (size_t)(m0+ar)*384 + ks + ah*16;
    s16x8 av0 = ((const s16x8*)as)[0];
    s16x8 av1 = ((const s16x8*)as)[1];
    const float* bs = W + (size_t)(j0+br)*384 + ks + bq*8;
    float4 b0 = ((const float4*)bs)[0], b1 = ((const float4*)bs)[1];
    *(s16x8*)&Al[ar*40 + ah*16]     = av0;
    *(s16x8*)&Al[ar*40 + ah*16 + 8] = av1;
    *(s16x8*)&Bl[br*40 + bq*8]      = pack8(b0,b1);
    __syncthreads();
    s16x8 af[4], bf[2];
    #pragma unroll
    for (int fm=0; fm<4; fm++) af[fm] = *(const s16x8*)&Al[(wr*64+fm*16+lr)*40 + g*8];
    #pragma unroll
    for (int fn=0; fn<2; fn++) bf[fn] = *(const s16x8*)&Bl[(wc*32+fn*16+lr)*40 + g*8];
    #pragma unroll
    for (int fm=0; fm<4; fm++)
      #pragma unroll
      for (int fn=0; fn<2; fn++)
        acc[fm][fn] = MFMA16(af[fm], bf[fn], acc[fm][fn]);
    __syncthreads();
  }
  float bs0 = bias[j0 + wc*32 + lr];
  float bs1 = bias[j0 + wc*32 + 16 + lr];
  #pragma unroll
  for (int fm=0; fm<4; fm++){
    #pragma unroll
    for (int jj=0; jj<4; jj++){
      int m = m0 + wr*64 + fm*16 + g*4 + jj;
      out[(size_t)m*384 + j0 + wc*32 + lr]      = acc[fm][0][jj] + bs0;
      out[(size_t)m*384 + j0 + wc*32 + 16 + lr] = acc[fm][1][jj] + bs1;
    }
  }
}

extern "C" void kernel_launch(void* const* d_in, const int* in_sizes, int n_in,
                              void* d_out, int out_size, void* d_ws, size_t ws_size,
                              hipStream_t stream) {
  const float* x     = (const float*)d_in[0];
  const float* vis   = (const float*)d_in[1];
  const float* wqkv  = (const float*)d_in[2];
  const float* wproj = (const float*)d_in[3];
  const float* bproj = (const float*)d_in[4];
  float* out = (float*)d_out;

  ushort* Qg = (ushort*)d_ws;
  ushort* Kg = Qg + SZ_;
  ushort* Vg = Kg + SZ_;
  ushort* AO = Vg + SZ_;

  qkv_gemm<<<dim3(98,18), 256, 0, stream>>>(x, wqkv, Qg, Kg, Vg);
  attn_fwd<<<dim3(48,25), 256, 0, stream>>>(Qg, Kg, Vg, vis, AO);
  proj_gemm<<<dim3(98,6), 256, 0, stream>>>(AO, wproj, bproj, out);
}